// Round 1
// baseline (669.455 us; speedup 1.0000x reference)
//
#include <hip/hip_runtime.h>

#define HH 32
#define TT 512
#define CHUNK 8
#define NCHUNK (TT / CHUNK)

__device__ __forceinline__ float fast_tanh(float z) {
    // tanh(z) = 1 - 2/(exp(2z)+1); exp2-based, ~1e-7 abs err
    float e, r;
    float zz = z * 2.88539008177793f;  // 2*log2(e)
    asm("v_exp_f32 %0, %1" : "=v"(e) : "v"(zz));
    float d = e + 1.0f;
    asm("v_rcp_f32 %0, %1" : "=v"(r) : "v"(d));
    return __builtin_fmaf(-2.0f, r, 1.0f);
}

// One wave = ONE batch, layers pipelined across wave halves:
//   lanes  0..31 (g=0): layer-1 row i, computes h1[s]   = tanh(b1 + W1·x[s]   + U1·h1[s-1])
//   lanes 32..63 (g=1): layer-2 row i, computes h2[s-1] = tanh(b2 + W2·h1[s-1] + U2·h2[s-2])
// h1[s-1] is wave-uniform -> broadcast via 32 v_readlane into SGPRs (no LDS),
// consumed as the SGPR operand of v_fmac. Only the divergent operand (x for
// g0, h2 for g1) goes through LDS: 8 ds_read_b128/step instead of 24.
// Weights: 2 matrices/lane = 64 VGPRs -> true live set ~115, honest 128-reg
// allocation at 4 waves/SIMD (no AGPR spill shuffles).
// Wave-synchronous: same-wave DS ops are processed in order; no barriers.
__global__ void __launch_bounds__(64) __attribute__((amdgpu_waves_per_eu(4, 4)))
rnn_fused(
    const float* __restrict__ x,
    const float* __restrict__ Wih1, const float* __restrict__ Whh1,
    const float* __restrict__ bih1, const float* __restrict__ bhh1,
    const float* __restrict__ Wih2, const float* __restrict__ Whh2,
    const float* __restrict__ bih2, const float* __restrict__ bhh2,
    const float* __restrict__ Wfc, const float* __restrict__ bfc,
    float* __restrict__ out)
{
    __shared__ __align__(16) float x_lds[CHUNK * HH];  // 1 KB, single buffer (same-wave in-order)
    __shared__ __align__(16) float h2_lds[HH];
    __shared__ __align__(16) float dump[HH];           // write sink for g0's h output

    const int lane = threadIdx.x;
    const int g = lane >> 5;
    const int i = lane & 31;
    const int b = blockIdx.x;

    // ---- weight rows in registers: 16 float4 = 64 VGPRs ----
    // g0: wa = W_ih1 row (x phase),  wb = W_hh1 row (h1 phase)
    // g1: wa = W_hh2 row (h2 phase), wb = W_ih2 row (h1 phase)
    const float* WaBase = g ? Whh2 : Wih1;
    const float* WbBase = g ? Wih2 : Whh1;
    float4 wa[8], wb[8];
#pragma unroll
    for (int q = 0; q < 8; ++q) {
        wa[q] = ((const float4*)(WaBase + i * HH))[q];
        wb[q] = ((const float4*)(WbBase + i * HH))[q];
    }
    const float bias = g ? (bih2[i] + bhh2[i]) : (bih1[i] + bhh1[i]);
    const float wfc = Wfc[i];

    const float* xb = x + (size_t)b * (TT * HH);

    // prefetch chunk 0: 8 steps x 32 floats = 64 float4, one per lane
    float4 r = ((const float4*)xb)[lane];

    float* wp = g ? &h2_lds[i] : &dump[i];
    h2_lds[i] = 0.0f;       // h2[-2] = 0 (both halves store same value)

    float hn = 0.0f;        // g0 lanes: h1[s-1] holder (h1[-1] = 0)
    const int pinc = g ? 0 : 8;  // vecA float4 step increment (x walks, h2 fixed)

    for (int c = 0; c < NCHUNK; ++c) {
        // commit staged x chunk (ds_write waits vmcnt for r internally)
        ((float4*)x_lds)[lane] = r;
        asm volatile("s_waitcnt lgkmcnt(0)" ::: "memory");
        // issue next chunk's global load — 8 steps (~2000 cyc) to hide it
        {
            const int cn = (c + 1 < NCHUNK) ? c + 1 : c;
            r = ((const float4*)(xb + cn * (CHUNK * HH)))[lane];
        }
        const float4* pA = (const float4*)(g ? h2_lds : x_lds);
#pragma unroll
        for (int s = 0; s < CHUNK; ++s) {
            // ---- h1[s-1] broadcast: 32 readlanes -> SGPRs (reads lanes 0..31) ----
            const int hb = __float_as_int(hn);
            float sh[32];
#pragma unroll
            for (int j = 0; j < 32; ++j)
                sh[j] = __int_as_float(__builtin_amdgcn_readlane(hb, j));

            // ---- dual dot: wa·vecA(LDS, divergent) + wb·h1(SGPR, uniform) ----
            float p0 = bias, p1 = 0.f, p2 = 0.f, p3 = 0.f;
#pragma unroll
            for (int j = 0; j < 8; ++j) {
                float4 av = pA[j];
                p0 = __builtin_fmaf(wa[j].x, av.x, p0);
                p1 = __builtin_fmaf(wa[j].y, av.y, p1);
                p2 = __builtin_fmaf(wa[j].z, av.z, p2);
                p3 = __builtin_fmaf(wa[j].w, av.w, p3);
                p0 = __builtin_fmaf(wb[j].x, sh[4 * j + 0], p0);
                p1 = __builtin_fmaf(wb[j].y, sh[4 * j + 1], p1);
                p2 = __builtin_fmaf(wb[j].z, sh[4 * j + 2], p2);
                p3 = __builtin_fmaf(wb[j].w, sh[4 * j + 3], p3);
            }
            float t = fast_tanh((p0 + p1) + (p2 + p3));

            // pipeline fill: at global step 0, g1's output slot is h2[-1] = 0
            float hw = t;
            if (s == 0 && c == 0 && g) hw = 0.0f;
            *wp = hw;          // g1 -> h2_lds[i]; g0 -> dump[i] (h1 travels via readlane)
            hn = t;
            pA += pinc;
        }
    }

    // ---- drain step: g1 computes h2[T-1] from h1[T-1] (readlane) + h2[T-2] (LDS) ----
    {
        const int hb = __float_as_int(hn);
        float sh[32];
#pragma unroll
        for (int j = 0; j < 32; ++j)
            sh[j] = __int_as_float(__builtin_amdgcn_readlane(hb, j));
        const float4* pA = (const float4*)h2_lds;   // uniform read; g0 result unused
        float p0 = bias, p1 = 0.f, p2 = 0.f, p3 = 0.f;
#pragma unroll
        for (int j = 0; j < 8; ++j) {
            float4 av = pA[j];
            p0 = __builtin_fmaf(wa[j].x, av.x, p0);
            p1 = __builtin_fmaf(wa[j].y, av.y, p1);
            p2 = __builtin_fmaf(wa[j].z, av.z, p2);
            p3 = __builtin_fmaf(wa[j].w, av.w, p3);
            p0 = __builtin_fmaf(wb[j].x, sh[4 * j + 0], p0);
            p1 = __builtin_fmaf(wb[j].y, sh[4 * j + 1], p1);
            p2 = __builtin_fmaf(wb[j].z, sh[4 * j + 2], p2);
            p3 = __builtin_fmaf(wb[j].w, sh[4 * j + 3], p3);
        }
        float t = fast_tanh((p0 + p1) + (p2 + p3));

        // ---- epilogue: out[b] = Wfc·h2[T-1] + bfc (h2 lives in upper lanes) ----
        float v = t * wfc;
        v += __shfl_xor(v, 1);
        v += __shfl_xor(v, 2);
        v += __shfl_xor(v, 4);
        v += __shfl_xor(v, 8);
        v += __shfl_xor(v, 16);
        if (lane == 32) out[b] = v + bfc[0];
    }
}

extern "C" void kernel_launch(void* const* d_in, const int* in_sizes, int n_in,
                              void* d_out, int out_size, void* d_ws, size_t ws_size,
                              hipStream_t stream) {
    const float* x    = (const float*)d_in[0];
    const float* Wih1 = (const float*)d_in[1];
    const float* Whh1 = (const float*)d_in[2];
    const float* bih1 = (const float*)d_in[3];
    const float* bhh1 = (const float*)d_in[4];
    const float* Wih2 = (const float*)d_in[5];
    const float* Whh2 = (const float*)d_in[6];
    const float* bih2 = (const float*)d_in[7];
    const float* bhh2 = (const float*)d_in[8];
    const float* Wfc  = (const float*)d_in[9];
    const float* bfc  = (const float*)d_in[10];
    float* out = (float*)d_out;

    rnn_fused<<<dim3(4096), dim3(64), 0, stream>>>(
        x, Wih1, Whh1, bih1, bhh1, Wih2, Whh2, bih2, bhh2, Wfc, bfc, out);
}

// Round 2
// 664.914 us; speedup vs baseline: 1.0068x; 1.0068x over previous
//
#include <hip/hip_runtime.h>

#define HH 32
#define TT 512
#define CHUNK 8
#define NCHUNK (TT / CHUNK)

__device__ __forceinline__ float fast_tanh(float z) {
    // tanh(z) = 1 - 2/(exp(2z)+1); exp2-based, ~1e-7 abs err
    float e, r;
    float zz = z * 2.88539008177793f;  // 2*log2(e)
    asm("v_exp_f32 %0, %1" : "=v"(e) : "v"(zz));
    float d = e + 1.0f;
    asm("v_rcp_f32 %0, %1" : "=v"(r) : "v"(d));
    return __builtin_fmaf(-2.0f, r, 1.0f);
}

// One wave = ONE batch, layers pipelined across wave halves:
//   lanes  0..31 (g=0): layer-1 row i, computes h1[s]   = tanh(b1 + W1·x[s]   + U1·h1[s-1])
//   lanes 32..63 (g=1): layer-2 row i, computes h2[s-1] = tanh(b2 + W2·h1[s-1] + U2·h2[s-2])
// h1[s-1] is wave-uniform -> broadcast via 32 v_readlane into SGPRs (no LDS),
// consumed as the SGPR src0 of v_fmac. Only the divergent operand (x for g0,
// h2 for g1) goes through LDS: 8 ds_read_b128/step instead of 24.
//
// REGISTER BUDGET (R1 post-mortem): the allocator budgets ~256/waves_per_eu
// VGPRs. (4,4) -> 64-reg allocation for a ~90-reg live set -> scratch/AGPR
// spill storm (WRITE_SIZE 61.5 MB, ~110 extra VALU/step). (2,2) -> 128-reg
// budget (verified R0); live set (64 weight regs + prefetch + temps) fits
// spill-free. VGPR<=128 still allows 4 waves/SIMD; occupancy stays
// grid-limited (16 waves/CU), the attribute does not cap HW residency.
__global__ void __launch_bounds__(64) __attribute__((amdgpu_waves_per_eu(2, 2)))
rnn_fused(
    const float* __restrict__ x,
    const float* __restrict__ Wih1, const float* __restrict__ Whh1,
    const float* __restrict__ bih1, const float* __restrict__ bhh1,
    const float* __restrict__ Wih2, const float* __restrict__ Whh2,
    const float* __restrict__ bih2, const float* __restrict__ bhh2,
    const float* __restrict__ Wfc, const float* __restrict__ bfc,
    float* __restrict__ out)
{
    __shared__ __align__(16) float x_lds[CHUNK * HH];  // 1 KB, single buffer (same-wave in-order)
    __shared__ __align__(16) float h2_lds[HH];
    __shared__ __align__(16) float dump[HH];           // write sink for g0's h output

    const int lane = threadIdx.x;
    const int g = lane >> 5;
    const int i = lane & 31;
    const int b = blockIdx.x;

    // ---- weight rows in registers: 16 float4 = 64 VGPRs ----
    // g0: wa = W_ih1 row (x phase),  wb = W_hh1 row (h1 phase)
    // g1: wa = W_hh2 row (h2 phase), wb = W_ih2 row (h1 phase)
    const float* WaBase = g ? Whh2 : Wih1;
    const float* WbBase = g ? Wih2 : Whh1;
    float4 wa[8], wb[8];
#pragma unroll
    for (int q = 0; q < 8; ++q) {
        wa[q] = ((const float4*)(WaBase + i * HH))[q];
        wb[q] = ((const float4*)(WbBase + i * HH))[q];
    }
    const float bias = g ? (bih2[i] + bhh2[i]) : (bih1[i] + bhh1[i]);
    const float wfc = Wfc[i];

    const float* xb = x + (size_t)b * (TT * HH);

    // prefetch chunk 0: 8 steps x 32 floats = 64 float4, one per lane
    float4 r = ((const float4*)xb)[lane];

    float* wp = g ? &h2_lds[i] : &dump[i];
    h2_lds[i] = 0.0f;       // h2[-2] = 0 (both halves store same value)

    float hn = 0.0f;        // g0 lanes: h1[s-1] holder (h1[-1] = 0)
    const int pinc = g ? 0 : 8;  // vecA float4 step increment (x walks, h2 fixed)

    for (int c = 0; c < NCHUNK; ++c) {
        // commit staged x chunk (ds_write waits vmcnt for r internally)
        ((float4*)x_lds)[lane] = r;
        asm volatile("s_waitcnt lgkmcnt(0)" ::: "memory");
        // issue next chunk's global load — 8 steps (~2000 cyc) to hide it
        {
            const int cn = (c + 1 < NCHUNK) ? c + 1 : c;
            r = ((const float4*)(xb + cn * (CHUNK * HH)))[lane];
        }
        const float4* pA = (const float4*)(g ? h2_lds : x_lds);
#pragma unroll
        for (int s = 0; s < CHUNK; ++s) {
            // ---- h1[s-1] broadcast: 32 readlanes -> SGPRs (reads lanes 0..31) ----
            const int hb = __float_as_int(hn);
            float sh[32];
#pragma unroll
            for (int j = 0; j < 32; ++j)
                sh[j] = __int_as_float(__builtin_amdgcn_readlane(hb, j));

            // ---- dual dot: wa·vecA(LDS, divergent) + wb·h1(SGPR, uniform) ----
            float p0 = bias, p1 = 0.f, p2 = 0.f, p3 = 0.f;
#pragma unroll
            for (int j = 0; j < 8; ++j) {
                float4 av = pA[j];
                p0 = __builtin_fmaf(wa[j].x, av.x, p0);
                p1 = __builtin_fmaf(wa[j].y, av.y, p1);
                p2 = __builtin_fmaf(wa[j].z, av.z, p2);
                p3 = __builtin_fmaf(wa[j].w, av.w, p3);
                p0 = __builtin_fmaf(wb[j].x, sh[4 * j + 0], p0);
                p1 = __builtin_fmaf(wb[j].y, sh[4 * j + 1], p1);
                p2 = __builtin_fmaf(wb[j].z, sh[4 * j + 2], p2);
                p3 = __builtin_fmaf(wb[j].w, sh[4 * j + 3], p3);
            }
            float t = fast_tanh((p0 + p1) + (p2 + p3));

            // pipeline fill: at global step 0, g1's output slot is h2[-1] = 0
            float hw = t;
            if (s == 0 && c == 0 && g) hw = 0.0f;
            *wp = hw;          // g1 -> h2_lds[i]; g0 -> dump[i] (h1 travels via readlane)
            hn = t;
            pA += pinc;
        }
    }

    // ---- drain step: g1 computes h2[T-1] from h1[T-1] (readlane) + h2[T-2] (LDS) ----
    {
        const int hb = __float_as_int(hn);
        float sh[32];
#pragma unroll
        for (int j = 0; j < 32; ++j)
            sh[j] = __int_as_float(__builtin_amdgcn_readlane(hb, j));
        const float4* pA = (const float4*)h2_lds;   // uniform read; g0 result unused
        float p0 = bias, p1 = 0.f, p2 = 0.f, p3 = 0.f;
#pragma unroll
        for (int j = 0; j < 8; ++j) {
            float4 av = pA[j];
            p0 = __builtin_fmaf(wa[j].x, av.x, p0);
            p1 = __builtin_fmaf(wa[j].y, av.y, p1);
            p2 = __builtin_fmaf(wa[j].z, av.z, p2);
            p3 = __builtin_fmaf(wa[j].w, av.w, p3);
            p0 = __builtin_fmaf(wb[j].x, sh[4 * j + 0], p0);
            p1 = __builtin_fmaf(wb[j].y, sh[4 * j + 1], p1);
            p2 = __builtin_fmaf(wb[j].z, sh[4 * j + 2], p2);
            p3 = __builtin_fmaf(wb[j].w, sh[4 * j + 3], p3);
        }
        float t = fast_tanh((p0 + p1) + (p2 + p3));

        // ---- epilogue: out[b] = Wfc·h2[T-1] + bfc (h2 lives in upper lanes) ----
        float v = t * wfc;
        v += __shfl_xor(v, 1);
        v += __shfl_xor(v, 2);
        v += __shfl_xor(v, 4);
        v += __shfl_xor(v, 8);
        v += __shfl_xor(v, 16);
        if (lane == 32) out[b] = v + bfc[0];
    }
}

extern "C" void kernel_launch(void* const* d_in, const int* in_sizes, int n_in,
                              void* d_out, int out_size, void* d_ws, size_t ws_size,
                              hipStream_t stream) {
    const float* x    = (const float*)d_in[0];
    const float* Wih1 = (const float*)d_in[1];
    const float* Whh1 = (const float*)d_in[2];
    const float* bih1 = (const float*)d_in[3];
    const float* bhh1 = (const float*)d_in[4];
    const float* Wih2 = (const float*)d_in[5];
    const float* Whh2 = (const float*)d_in[6];
    const float* bih2 = (const float*)d_in[7];
    const float* bhh2 = (const float*)d_in[8];
    const float* Wfc  = (const float*)d_in[9];
    const float* bfc  = (const float*)d_in[10];
    float* out = (float*)d_out;

    rnn_fused<<<dim3(4096), dim3(64), 0, stream>>>(
        x, Wih1, Whh1, bih1, bhh1, Wih2, Whh2, bih2, bhh2, Wfc, bfc, out);
}

// Round 3
// 553.687 us; speedup vs baseline: 1.2091x; 1.2009x over previous
//
#include <hip/hip_runtime.h>

#define HH 32
#define TT 512
#define CHUNK 8
#define NCHUNK (TT / CHUNK)

__device__ __forceinline__ float fast_tanh(float z) {
    // tanh(z) = 1 - 2/(exp(2z)+1); exp2-based, ~1e-7 abs err
    float e, r;
    float zz = z * 2.88539008177793f;  // 2*log2(e)
    asm("v_exp_f32 %0, %1" : "=v"(e) : "v"(zz));
    float d = e + 1.0f;
    asm("v_rcp_f32 %0, %1" : "=v"(r) : "v"(d));
    return __builtin_fmaf(-2.0f, r, 1.0f);
}

// One wave/block; lanes 0..31 = batch b0, lanes 32..63 = batch b1.
// Lane owns hidden row i of all 4 weight matrices in VGPRs (128 regs).
// h/x broadcast via group-uniform ds_read_b128 — each b128 slot serves BOTH
// batches via divergent group addressing (transport-optimal: 12 LDS
// instrs/batch-step). Wave-synchronous fences (s_waitcnt lgkmcnt(0)) instead
// of __syncthreads — no vmcnt drain, so the x prefetch stays in flight.
//
// REGISTER BUDGET (R1/R2 post-mortem): allocator budget = 256/min_waves_per_eu.
// (2,2) gave a 128-reg allocation for this ~195-reg live set -> AGPR-shuffle
// spills (~185 extra VALU/step, VALUBusy 86%). (1,2) -> 256-reg budget: live
// set fits spill-free; VGPR ~200 still allows 2 waves/SIMD residency (HW file
// = 512/SIMD), and grid 2048 waves = exactly 2/SIMD, all resident.
// This round discriminates: if dur stays ~330 µs the LDS pipe (8 cyc/b128
// broadcast) is the wall; if broadcasts are cheaper we land 170-250 µs.
__global__ void __launch_bounds__(64) __attribute__((amdgpu_waves_per_eu(1, 2)))
rnn_fused(
    const float* __restrict__ x,
    const float* __restrict__ Wih1, const float* __restrict__ Whh1,
    const float* __restrict__ bih1, const float* __restrict__ bhh1,
    const float* __restrict__ Wih2, const float* __restrict__ Whh2,
    const float* __restrict__ bih2, const float* __restrict__ bhh2,
    const float* __restrict__ Wfc, const float* __restrict__ bfc,
    float* __restrict__ out)
{
    __shared__ __align__(16) float x_lds[2][CHUNK * HH];
    __shared__ __align__(16) float h1_lds[2][HH];
    __shared__ __align__(16) float h2_lds[2][HH];

    const int lane = threadIdx.x;
    const int g = lane >> 5;
    const int i = lane & 31;
    const int b = blockIdx.x * 2 + g;

    // ---- weight rows in registers: 32 float4 = 128 VGPRs ----
    float4 w1[8], u1[8], w2[8], u2[8];
#pragma unroll
    for (int q = 0; q < 8; ++q) {
        w1[q] = ((const float4*)(Wih1 + i * HH))[q];
        u1[q] = ((const float4*)(Whh1 + i * HH))[q];
        w2[q] = ((const float4*)(Wih2 + i * HH))[q];
        u2[q] = ((const float4*)(Whh2 + i * HH))[q];
    }
    const float bias1 = bih1[i] + bhh1[i];
    const float bias2 = bih2[i] + bhh2[i];
    const float wfc = Wfc[i];

    const float* xb = x + (size_t)b * (TT * HH);

    // prefetch chunk 0 (8 timesteps = 64 float4 per group)
    float4 r0 = ((const float4*)xb)[i];
    float4 r1 = ((const float4*)xb)[i + 32];

    // h1_{t-1} broadcast values, live across steps in regs (no copy movs)
    float4 h1r[8];
#pragma unroll
    for (int j = 0; j < 8; ++j) h1r[j] = make_float4(0.f, 0.f, 0.f, 0.f);
    float h2_own = 0.0f;
    h2_lds[g][i] = 0.0f;  // h2_{-1}=0; visible after first chunk fence

    float4* xl4 = (float4*)&x_lds[g][0];
    const float4* h1l4 = (const float4*)&h1_lds[g][0];
    const float4* h2l4 = (const float4*)&h2_lds[g][0];

    for (int c = 0; c < NCHUNK; ++c) {
        // commit staged x chunk (ds_write waits vmcnt for r0/r1 internally)
        xl4[i] = r0;
        xl4[i + 32] = r1;
        asm volatile("s_waitcnt lgkmcnt(0)" ::: "memory");
        // issue next chunk's global loads — 8 steps (~2500 cyc) to hide them
        {
            const int cn = (c + 1 < NCHUNK) ? c + 1 : c;
            const float4* src = (const float4*)(xb + cn * (CHUNK * HH));
            r0 = src[i];
            r1 = src[i + 32];
        }
#pragma unroll
        for (int s = 0; s < CHUNK; ++s) {
            // ---- layer 1: bias1 + W_ih1[i,:]·x_t + W_hh1[i,:]·h1_{t-1} ----
            float p0 = bias1, p1 = 0.f, p2 = 0.f, p3 = 0.f;
#pragma unroll
            for (int j = 0; j < 8; ++j) {
                float4 xv = xl4[s * 8 + j];  // immediate-offset broadcast read
                p0 = __builtin_fmaf(w1[j].x, xv.x, p0);
                p1 = __builtin_fmaf(w1[j].y, xv.y, p1);
                p2 = __builtin_fmaf(w1[j].z, xv.z, p2);
                p3 = __builtin_fmaf(w1[j].w, xv.w, p3);
            }
#pragma unroll
            for (int j = 0; j < 8; ++j) {
                p0 = __builtin_fmaf(u1[j].x, h1r[j].x, p0);
                p1 = __builtin_fmaf(u1[j].y, h1r[j].y, p1);
                p2 = __builtin_fmaf(u1[j].z, h1r[j].z, p2);
                p3 = __builtin_fmaf(u1[j].w, h1r[j].w, p3);
            }
            float h1n = fast_tanh((p0 + p1) + (p2 + p3));
            h1_lds[g][i] = h1n;
            asm volatile("s_waitcnt lgkmcnt(0)" ::: "memory");  // h1_t + h2_{t-1} visible

            // ---- layer 2: bias2 + W_ih2[i,:]·h1_t + W_hh2[i,:]·h2_{t-1} ----
            float q0 = bias2, q1 = 0.f, q2 = 0.f, q3 = 0.f;
#pragma unroll
            for (int j = 0; j < 8; ++j) {
                float4 h1v = h1l4[j];
                float4 h2v = h2l4[j];
                h1r[j] = h1v;  // SSA rename: becomes next step's h1_{t-1}
                q0 = __builtin_fmaf(w2[j].x, h1v.x, q0);
                q1 = __builtin_fmaf(w2[j].y, h1v.y, q1);
                q2 = __builtin_fmaf(w2[j].z, h1v.z, q2);
                q3 = __builtin_fmaf(w2[j].w, h1v.w, q3);
                q0 = __builtin_fmaf(u2[j].x, h2v.x, q0);
                q1 = __builtin_fmaf(u2[j].y, h2v.y, q1);
                q2 = __builtin_fmaf(u2[j].z, h2v.z, q2);
                q3 = __builtin_fmaf(u2[j].w, h2v.w, q3);
            }
            float h2n = fast_tanh((q0 + q1) + (q2 + q3));
            h2_own = h2n;
            h2_lds[g][i] = h2n;  // visibility via next step's fence
        }
    }

    // ---- epilogue: out[b] = Σ_i h2[i]*Wfc[i] + bfc ----
    h1_lds[g][i] = h2_own * wfc;
    asm volatile("s_waitcnt lgkmcnt(0)" ::: "memory");
    if (i == 0) {
        float sacc = bfc[0];
#pragma unroll
        for (int j = 0; j < HH; ++j) sacc += h1_lds[g][j];
        out[b] = sacc;
    }
}

extern "C" void kernel_launch(void* const* d_in, const int* in_sizes, int n_in,
                              void* d_out, int out_size, void* d_ws, size_t ws_size,
                              hipStream_t stream) {
    const float* x    = (const float*)d_in[0];
    const float* Wih1 = (const float*)d_in[1];
    const float* Whh1 = (const float*)d_in[2];
    const float* bih1 = (const float*)d_in[3];
    const float* bhh1 = (const float*)d_in[4];
    const float* Wih2 = (const float*)d_in[5];
    const float* Whh2 = (const float*)d_in[6];
    const float* bih2 = (const float*)d_in[7];
    const float* bhh2 = (const float*)d_in[8];
    const float* Wfc  = (const float*)d_in[9];
    const float* bfc  = (const float*)d_in[10];
    float* out = (float*)d_out;

    rnn_fused<<<dim3(2048), dim3(64), 0, stream>>>(
        x, Wih1, Whh1, bih1, bhh1, Wih2, Whh2, bih2, bhh2, Wfc, bfc, out);
}